// Round 7
// baseline (272.383 us; speedup 1.0000x reference)
//
#include <hip/hip_runtime.h>
#include <stdint.h>

typedef __bf16 bf16;
typedef __bf16 bf16x4 __attribute__((ext_vector_type(4)));
typedef __bf16 bf16x8 __attribute__((ext_vector_type(8)));
typedef float f32x4 __attribute__((ext_vector_type(4)));
typedef float f32x16 __attribute__((ext_vector_type(16)));

#define MFMA32(a, b, c) __builtin_amdgcn_mfma_f32_32x32x16_bf16((a), (b), (c), 0, 0, 0)

// Async global->LDS, 16 B per lane: lane i's 16 B lands at ldsbase + i*16
// (wave-uniform base, m104/m108). Global address is per-lane.
__device__ __forceinline__ void gload16(const bf16* g, bf16* l) {
    __builtin_amdgcn_global_load_lds(
        (const __attribute__((address_space(1))) void*)g,
        (__attribute__((address_space(3))) void*)l, 16, 0, 0);
}

// ---------------------------------------------------------------------------
// fp32 -> bf16 for q,k,v (4M each) and Wq,Wk,Wv,Wo (1M each).
// ---------------------------------------------------------------------------
__global__ __launch_bounds__(256) void cvt_kernel(
    const float* __restrict__ q, const float* __restrict__ k, const float* __restrict__ v,
    const float* __restrict__ wq, const float* __restrict__ wk,
    const float* __restrict__ wv, const float* __restrict__ wo,
    bf16* __restrict__ qb, bf16* __restrict__ kb, bf16* __restrict__ vb,
    bf16* __restrict__ wqb, bf16* __restrict__ wkb, bf16* __restrict__ wvb,
    bf16* __restrict__ wob)
{
    int z = blockIdx.z;
    const float* src; bf16* dst; int n;
    switch (z) {
        case 0:  src = q;  dst = qb;  n = 4194304; break;
        case 1:  src = k;  dst = kb;  n = 4194304; break;
        case 2:  src = v;  dst = vb;  n = 4194304; break;
        case 3:  src = wq; dst = wqb; n = 1048576; break;
        case 4:  src = wk; dst = wkb; n = 1048576; break;
        case 5:  src = wv; dst = wvb; n = 1048576; break;
        default: src = wo; dst = wob; n = 1048576; break;
    }
    int i = (blockIdx.x * 256 + threadIdx.x) * 8;
    if (i >= n) return;
    float4 f0 = *(const float4*)(src + i);
    float4 f1 = *(const float4*)(src + i + 4);
    bf16x8 o;
    o[0] = (bf16)f0.x; o[1] = (bf16)f0.y; o[2] = (bf16)f0.z; o[3] = (bf16)f0.w;
    o[4] = (bf16)f1.x; o[5] = (bf16)f1.y; o[6] = (bf16)f1.z; o[7] = (bf16)f1.w;
    *(bf16x8*)(dst + i) = o;
}

// ---------------------------------------------------------------------------
// mask [2048][2048] int32 -> maskb [2048][32] uint64 via __ballot.
// ---------------------------------------------------------------------------
__global__ __launch_bounds__(256) void maskpack_kernel(
    const int* __restrict__ mask, unsigned long long* __restrict__ maskb)
{
    int gid  = blockIdx.x * 256 + threadIdx.x;
    int word = gid >> 6;
    int lane = gid & 63;
    int row = word >> 5, wc = word & 31;
    int mv = mask[row * 2048 + wc * 64 + lane];
    unsigned long long bits = __ballot(mv != 0);
    if (lane == 0) maskb[word] = bits;
}

// ---------------------------------------------------------------------------
// NT GEMM v7 (bf16): C[m][n] = sum_k A[m][k]*B[n][k], K=1024, N=1024, M=4096.
// MT x 128 tile, BK=64 (16 iters -> half the barrier drains of BK=32),
// 32x32x16 MFMA (half the MFMA instrs of 16x16x32 at better cyc/FLOP).
// LDS unpadded [row][64] XOR-swizzled (chunk ^= row&7): DMA writes linear,
// frag reads <=4-way banks. Wave = (MT/2) x 64 of 32x32 tiles.
// OUTMODE 0: bf16 out, z selects {Q,K,V}; z==0 (Q) pre-scaled by log2(e)/32
// (energy scale + exp->exp2 fold); z==2 (V) written direct-transposed to
// Vt[b][feature][s] (C-layout: 4 consecutive s per lane -> bf16x4 stores).
// OUTMODE 1: fp32 out + bias.
// 32x32 layouts (m74/m101): C/D col=lane&31, row=(reg&3)+8*(reg>>2)+4*(lane>>5);
// A[m=lane&31][k=(lane>>5)*8+j]; B[k=(lane>>5)*8+j][n=lane&31].
// ---------------------------------------------------------------------------
template <int OUTMODE, int MT>
__global__ __launch_bounds__(256) void gemm_kernel(
    const bf16* __restrict__ A0, const bf16* __restrict__ A1, const bf16* __restrict__ A2,
    const bf16* __restrict__ B0, const bf16* __restrict__ B1, const bf16* __restrict__ B2,
    bf16* __restrict__ C0, bf16* __restrict__ C1, bf16* __restrict__ C2,
    const float* __restrict__ bias, float* __restrict__ outf)
{
    constexpr int MTw = MT / 64;   // 32-row m-tiles per wave (2 or 1)

    const int z = blockIdx.z;
    const bf16* A = (z == 0) ? A0 : (z == 1) ? A1 : A2;
    const bf16* B = (z == 0) ? B0 : (z == 1) ? B1 : B2;

    __shared__ bf16 At[MT * 64];
    __shared__ bf16 Bt[128 * 64];

    const int tid  = threadIdx.x;
    const int lane = tid & 63;
    const int wave = tid >> 6;
    const int l32  = lane & 31;
    const int hl   = lane >> 5;
    const int l7   = lane & 7;
    const int wm = (wave >> 1) * (MT / 2);
    const int wn = (wave & 1) * 64;
    const int m0 = blockIdx.y * MT;
    const int n0 = blockIdx.x * 128;

    // DMA per-lane base: local row i>>3, LDS chunk i&7, global chunk (i&7)^(i>>3)
    const int dmarow = lane >> 3;
    const int dmacol = ((lane & 7) ^ dmarow) * 8;
    const bf16* Ag = A + (size_t)(m0 + dmarow) * 1024 + dmacol;
    const bf16* Bg = B + (size_t)(n0 + dmarow) * 1024 + dmacol;

    f32x16 acc[MTw][2] = {};

    for (int k0 = 0; k0 < 1024; k0 += 64) {
        __syncthreads();                 // prev iteration's frag reads done
#pragma unroll
        for (int j = 0; j < MT / 32; ++j) {
            int rb = wave * (MT / 4) + j * 8;
            gload16(Ag + (size_t)rb * 1024 + k0, At + rb * 64);
        }
#pragma unroll
        for (int j = 0; j < 4; ++j) {
            int rb = wave * 32 + j * 8;
            gload16(Bg + (size_t)rb * 1024 + k0, Bt + rb * 64);
        }
        __syncthreads();                 // vmcnt(0) drained before barrier

#pragma unroll
        for (int ks = 0; ks < 4; ++ks) {
            const int cidx = (((ks * 2 + hl) ^ l7) * 8);
            bf16x8 af[MTw], bg[2];
#pragma unroll
            for (int mt = 0; mt < MTw; ++mt)
                af[mt] = *(const bf16x8*)(At + (wm + mt * 32 + l32) * 64 + cidx);
#pragma unroll
            for (int nt = 0; nt < 2; ++nt)
                bg[nt] = *(const bf16x8*)(Bt + (wn + nt * 32 + l32) * 64 + cidx);
#pragma unroll
            for (int mt = 0; mt < MTw; ++mt)
#pragma unroll
                for (int nt = 0; nt < 2; ++nt)
                    acc[mt][nt] = MFMA32(af[mt], bg[nt], acc[mt][nt]);
        }
    }

    // C/D: col = l32, row = (r&3) + 8*(r>>2) + 4*hl
    if constexpr (OUTMODE == 0) {
        if (z == 2) {
            // direct-transpose: Vt[(row>>11)*1024 + col][row & 2047]
#pragma unroll
            for (int mt = 0; mt < MTw; ++mt)
#pragma unroll
                for (int nt = 0; nt < 2; ++nt)
#pragma unroll
                    for (int g = 0; g < 4; ++g) {
                        int row = m0 + wm + mt * 32 + 4 * hl + 8 * g;
                        int col = n0 + wn + nt * 32 + l32;
                        bf16x4 pv;
#pragma unroll
                        for (int r = 0; r < 4; ++r) pv[r] = (bf16)acc[mt][nt][g * 4 + r];
                        *(bf16x4*)(C2 + ((size_t)((row >> 11) * 1024 + col)) * 2048 +
                                   (row & 2047)) = pv;
                    }
        } else {
            bf16* C = (z == 0) ? C0 : C1;
            const float cs = (z == 0) ? 0.04508422f : 1.0f;  // log2(e)/32
#pragma unroll
            for (int mt = 0; mt < MTw; ++mt)
#pragma unroll
                for (int nt = 0; nt < 2; ++nt) {
                    int col = n0 + wn + nt * 32 + l32;
#pragma unroll
                    for (int g = 0; g < 4; ++g) {
                        int row = m0 + wm + mt * 32 + 4 * hl + 8 * g;
#pragma unroll
                        for (int r = 0; r < 4; ++r)
                            C[(size_t)(row + r) * 1024 + col] =
                                (bf16)(acc[mt][nt][g * 4 + r] * cs);
                    }
                }
        }
    } else {
#pragma unroll
        for (int nt = 0; nt < 2; ++nt) {
            int col = n0 + wn + nt * 32 + l32;
            float bj = bias[col];
#pragma unroll
            for (int mt = 0; mt < MTw; ++mt)
#pragma unroll
                for (int g = 0; g < 4; ++g) {
                    int row = m0 + wm + mt * 32 + 4 * hl + 8 * g;
#pragma unroll
                    for (int r = 0; r < 4; ++r)
                        outf[(size_t)(row + r) * 1024 + col] =
                            acc[mt][nt][g * 4 + r] + bj;
                }
        }
    }
}

// ---------------------------------------------------------------------------
// Flash attention v7 = R5 structure (best measured: 76 us) + exp2 fold.
// Block = 128 q x 64-key tile of one (b,h); 4 waves x 32 q, each wave the
// FULL 64 keys (per-iter amortization beats occupancy: R6's split-K at 36%
// occ was slower than this at 18%). 32x32x16 MFMA. K/V: unpadded XOR-swizzled
// LDS via global_load_lds DMA. Max-free linear softmax (energies ~|0.7|),
// bit-packed mask, row-sum via ones-MFMA. Q pre-scaled by log2(e)/32 ->
// exp2f = bare v_exp_f32.
// ---------------------------------------------------------------------------
__global__ __launch_bounds__(256) void flash_kernel(
    const bf16* __restrict__ Q, const bf16* __restrict__ K, const bf16* __restrict__ Vt,
    const unsigned long long* __restrict__ maskb, bf16* __restrict__ O)
{
    __shared__ bf16 Kl[64 * 64];     // [key][d-chunk swizzled]
    __shared__ bf16 Vl[64 * 64];     // [d][key-chunk swizzled]
    __shared__ bf16 Pl[128 * 72];    // [q][key+pad]

    const int tid  = threadIdx.x;
    const int lane = tid & 63;
    const int wave = tid >> 6;       // q-tile 0..3
    const int l32  = lane & 31;
    const int hl   = lane >> 5;
    const int l7   = lane & 7;
    const int b  = blockIdx.z;
    const int h  = blockIdx.y;
    const int q0 = blockIdx.x * 128;
    const int qt = q0 + wave * 32;

    // Q B-frags: B[k=d(hl*8+j)][n=q(l32)], 4 k-steps of 16
    const bf16* Qb = Q + (size_t)(b * 2048 + qt + l32) * 1024 + h * 64 + hl * 8;
    bf16x8 qf[4];
#pragma unroll
    for (int ks = 0; ks < 4; ++ks) qf[ks] = *(const bf16x8*)(Qb + ks * 16);

    bf16x8 ones;
#pragma unroll
    for (int j = 0; j < 8; ++j) ones[j] = (bf16)1.0f;

    f32x16 acc[2] = {};
    f32x16 lacc = {};

    // DMA staging: wave stages K rows wave*16..+15 and V rows wave*16..+15,
    // 2 calls each (8 rows/call). Lane i -> row i>>3, LDS chunk i&7,
    // global chunk (i&7)^(i>>3).
    const int dmarow = lane >> 3;
    const int dmacol = (l7 ^ dmarow) * 8;
    const bf16* Kg = K + (size_t)(b * 2048 + wave * 16 + dmarow) * 1024 + h * 64 + dmacol;
    const bf16* Vg = Vt + (size_t)((b * 16 + h) * 64 + wave * 16 + dmarow) * 2048 + dmacol;
    bf16* Kw = Kl + (wave * 16) * 64;
    bf16* Vw = Vl + (wave * 16) * 64;
    const unsigned long long* Mg = maskb + (size_t)(qt + l32) * 32;

    bf16* Pq = Pl + (wave * 32 + l32) * 72;

    for (int kt = 0; kt < 2048; kt += 64) {
        unsigned long long mw = Mg[kt >> 6];
        __syncthreads();                 // prev iteration's frag reads done
        gload16(Kg + (size_t)kt * 1024,       Kw);
        gload16(Kg + (size_t)(kt + 8) * 1024, Kw + 8 * 64);
        gload16(Vg + kt,                      Vw);
        gload16(Vg + kt + 8 * 2048,           Vw + 8 * 64);
        __syncthreads();                 // vmcnt(0) drained before barrier

        // S^T = K Q^T: two 32-key tiles, C[m=key][n=q]
#pragma unroll
        for (int t = 0; t < 2; ++t) {
            f32x16 s = {};
#pragma unroll
            for (int ks = 0; ks < 4; ++ks) {
                bf16x8 ka = *(const bf16x8*)(Kl + (t * 32 + l32) * 64 +
                                             (((ks * 2 + hl) ^ l7) * 8));
                s = MFMA32(ka, qf[ks], s);
            }
            // mask + exp2 -> P[q][key] (reg g*4+r -> key t*32 + 4hl + 8g + r)
            unsigned long long mwt = mw >> (t * 32 + 4 * hl);
#pragma unroll
            for (int g = 0; g < 4; ++g) {
                bf16x4 pv;
#pragma unroll
                for (int r = 0; r < 4; ++r) {
                    bool keep = (mwt >> (8 * g + r)) & 1ULL;
                    float e = exp2f(s[g * 4 + r]);   // Q pre-scaled by log2e/32
                    pv[r] = keep ? (bf16)e : (bf16)0.0f;
                }
                *(bf16x4*)(Pq + t * 32 + 4 * hl + 8 * g) = pv;
            }
        }

        // PV: A=P[m=q][k=key] (wave-private roundtrip, no barrier),
        //     B=V^T[k=key][n=d] from swizzled Vl
        bf16x8 pa[4];
#pragma unroll
        for (int ks = 0; ks < 4; ++ks)
            pa[ks] = *(const bf16x8*)(Pq + ks * 16 + hl * 8);
#pragma unroll
        for (int dt = 0; dt < 2; ++dt)
#pragma unroll
            for (int ks = 0; ks < 4; ++ks) {
                bf16x8 vb = *(const bf16x8*)(Vl + (dt * 32 + l32) * 64 +
                                             (((ks * 2 + hl) ^ l7) * 8));
                acc[dt] = MFMA32(pa[ks], vb, acc[dt]);
            }
#pragma unroll
        for (int ks = 0; ks < 4; ++ks)
            lacc = MFMA32(pa[ks], ones, lacc);   // row-sums, all n identical
    }

    // Epilogue: row q_rel = 4hl + 8g + r, col d = dt*32 + l32
    const size_t obase = (size_t)(b * 2048 + qt) * 1024 + h * 64;
#pragma unroll
    for (int g = 0; g < 4; ++g)
#pragma unroll
        for (int r = 0; r < 4; ++r) {
            int qr = 4 * hl + 8 * g + r;
            float inv = 1.0f / lacc[g * 4 + r];
            O[obase + (size_t)qr * 1024 + l32]      = (bf16)(acc[0][g * 4 + r] * inv);
            O[obase + (size_t)qr * 1024 + 32 + l32] = (bf16)(acc[1][g * 4 + r] * inv);
        }
}

// ---------------------------------------------------------------------------
extern "C" void kernel_launch(void* const* d_in, const int* in_sizes, int n_in,
                              void* d_out, int out_size, void* d_ws, size_t ws_size,
                              hipStream_t stream)
{
    const float* q  = (const float*)d_in[0];
    const float* k  = (const float*)d_in[1];
    const float* v  = (const float*)d_in[2];
    const int* mask = (const int*)d_in[3];
    const float* wq = (const float*)d_in[4];
    const float* wk = (const float*)d_in[5];
    const float* wv = (const float*)d_in[6];
    const float* wo = (const float*)d_in[7];
    const float* bo = (const float*)d_in[8];
    float* out = (float*)d_out;

    char* p = (char*)d_ws;
    auto alloc = [&](size_t bytes) {
        char* r = p;
        p += (bytes + 255) & ~(size_t)255;
        return r;
    };
    const size_t SB = (size_t)4096 * 1024 * 2;
    const size_t WB = (size_t)1024 * 1024 * 2;
    bf16* qb  = (bf16*)alloc(SB);
    bf16* kb  = (bf16*)alloc(SB);
    bf16* vb  = (bf16*)alloc(SB);
    bf16* wqb = (bf16*)alloc(WB);
    bf16* wkb = (bf16*)alloc(WB);
    bf16* wvb = (bf16*)alloc(WB);
    bf16* wob = (bf16*)alloc(WB);
    bf16* Qp  = (bf16*)alloc(SB);
    bf16* Kp  = (bf16*)alloc(SB);
    bf16* Vtp = (bf16*)alloc(SB);
    bf16* Ob  = (bf16*)alloc(SB);
    unsigned long long* maskb = (unsigned long long*)alloc(2048 * 32 * 8);

    cvt_kernel<<<dim3(2048, 1, 7), 256, 0, stream>>>(
        q, k, v, wq, wk, wv, wo, qb, kb, vb, wqb, wkb, wvb, wob);

    maskpack_kernel<<<dim3(16384), 256, 0, stream>>>(mask, maskb);

    // z=2 (V) writes direct-transposed into Vtp
    gemm_kernel<0, 128><<<dim3(8, 32, 3), 256, 0, stream>>>(
        qb, kb, vb, wqb, wkb, wvb, Qp, Kp, Vtp, nullptr, nullptr);

    flash_kernel<<<dim3(16, 16, 2), 256, 0, stream>>>(Qp, Kp, Vtp, maskb, Ob);

    gemm_kernel<1, 64><<<dim3(8, 64, 1), 256, 0, stream>>>(
        Ob, nullptr, nullptr, wob, nullptr, nullptr,
        nullptr, nullptr, nullptr, bo, out);
}

// Round 8
// 257.931 us; speedup vs baseline: 1.0560x; 1.0560x over previous
//
#include <hip/hip_runtime.h>
#include <stdint.h>

typedef __bf16 bf16;
typedef __bf16 bf16x4 __attribute__((ext_vector_type(4)));
typedef __bf16 bf16x8 __attribute__((ext_vector_type(8)));
typedef float f32x4 __attribute__((ext_vector_type(4)));
typedef float f32x16 __attribute__((ext_vector_type(16)));

#define MFMA32(a, b, c) __builtin_amdgcn_mfma_f32_32x32x16_bf16((a), (b), (c), 0, 0, 0)

// Async global->LDS, 16 B per lane: lane i's 16 B lands at ldsbase + i*16
// (wave-uniform base, m104/m108). Global address is per-lane.
__device__ __forceinline__ void gload16(const bf16* g, bf16* l) {
    __builtin_amdgcn_global_load_lds(
        (const __attribute__((address_space(1))) void*)g,
        (__attribute__((address_space(3))) void*)l, 16, 0, 0);
}

// ---------------------------------------------------------------------------
// fp32 -> bf16 for q,k,v (4M each) and Wq,Wk,Wv,Wo (1M each).
// ---------------------------------------------------------------------------
__global__ __launch_bounds__(256) void cvt_kernel(
    const float* __restrict__ q, const float* __restrict__ k, const float* __restrict__ v,
    const float* __restrict__ wq, const float* __restrict__ wk,
    const float* __restrict__ wv, const float* __restrict__ wo,
    bf16* __restrict__ qb, bf16* __restrict__ kb, bf16* __restrict__ vb,
    bf16* __restrict__ wqb, bf16* __restrict__ wkb, bf16* __restrict__ wvb,
    bf16* __restrict__ wob)
{
    int z = blockIdx.z;
    const float* src; bf16* dst; int n;
    switch (z) {
        case 0:  src = q;  dst = qb;  n = 4194304; break;
        case 1:  src = k;  dst = kb;  n = 4194304; break;
        case 2:  src = v;  dst = vb;  n = 4194304; break;
        case 3:  src = wq; dst = wqb; n = 1048576; break;
        case 4:  src = wk; dst = wkb; n = 1048576; break;
        case 5:  src = wv; dst = wvb; n = 1048576; break;
        default: src = wo; dst = wob; n = 1048576; break;
    }
    int i = (blockIdx.x * 256 + threadIdx.x) * 8;
    if (i >= n) return;
    float4 f0 = *(const float4*)(src + i);
    float4 f1 = *(const float4*)(src + i + 4);
    bf16x8 o;
    o[0] = (bf16)f0.x; o[1] = (bf16)f0.y; o[2] = (bf16)f0.z; o[3] = (bf16)f0.w;
    o[4] = (bf16)f1.x; o[5] = (bf16)f1.y; o[6] = (bf16)f1.z; o[7] = (bf16)f1.w;
    *(bf16x8*)(dst + i) = o;
}

// ---------------------------------------------------------------------------
// mask [2048][2048] int32 -> maskb [2048][32] uint64 via __ballot.
// ---------------------------------------------------------------------------
__global__ __launch_bounds__(256) void maskpack_kernel(
    const int* __restrict__ mask, unsigned long long* __restrict__ maskb)
{
    int gid  = blockIdx.x * 256 + threadIdx.x;
    int word = gid >> 6;
    int lane = gid & 63;
    int row = word >> 5, wc = word & 31;
    int mv = mask[row * 2048 + wc * 64 + lane];
    unsigned long long bits = __ballot(mv != 0);
    if (lane == 0) maskb[word] = bits;
}

// ---------------------------------------------------------------------------
// NT GEMM v7 (bf16), unchanged from R7 (measured neutral vs R5, fewer instrs):
// MT x 128 tile, BK=64, 32x32x16 MFMA, XOR-swizzled LDS, global_load_lds DMA.
// OUTMODE 0: bf16 out, z selects {Q,K,V}; z==0 (Q) pre-scaled by log2(e)/32;
// z==2 (V) written direct-transposed to Vt[b][feature][s].
// OUTMODE 1: fp32 out + bias.
// 32x32 layouts (m74/m101): C/D col=lane&31, row=(reg&3)+8*(reg>>2)+4*(lane>>5);
// A[m=lane&31][k=(lane>>5)*8+j]; B[k=(lane>>5)*8+j][n=lane&31].
// ---------------------------------------------------------------------------
template <int OUTMODE, int MT>
__global__ __launch_bounds__(256) void gemm_kernel(
    const bf16* __restrict__ A0, const bf16* __restrict__ A1, const bf16* __restrict__ A2,
    const bf16* __restrict__ B0, const bf16* __restrict__ B1, const bf16* __restrict__ B2,
    bf16* __restrict__ C0, bf16* __restrict__ C1, bf16* __restrict__ C2,
    const float* __restrict__ bias, float* __restrict__ outf)
{
    constexpr int MTw = MT / 64;   // 32-row m-tiles per wave (2 or 1)

    const int z = blockIdx.z;
    const bf16* A = (z == 0) ? A0 : (z == 1) ? A1 : A2;
    const bf16* B = (z == 0) ? B0 : (z == 1) ? B1 : B2;

    __shared__ bf16 At[MT * 64];
    __shared__ bf16 Bt[128 * 64];

    const int tid  = threadIdx.x;
    const int lane = tid & 63;
    const int wave = tid >> 6;
    const int l32  = lane & 31;
    const int hl   = lane >> 5;
    const int l7   = lane & 7;
    const int wm = (wave >> 1) * (MT / 2);
    const int wn = (wave & 1) * 64;
    const int m0 = blockIdx.y * MT;
    const int n0 = blockIdx.x * 128;

    const int dmarow = lane >> 3;
    const int dmacol = ((lane & 7) ^ dmarow) * 8;
    const bf16* Ag = A + (size_t)(m0 + dmarow) * 1024 + dmacol;
    const bf16* Bg = B + (size_t)(n0 + dmarow) * 1024 + dmacol;

    f32x16 acc[MTw][2] = {};

    for (int k0 = 0; k0 < 1024; k0 += 64) {
        __syncthreads();
#pragma unroll
        for (int j = 0; j < MT / 32; ++j) {
            int rb = wave * (MT / 4) + j * 8;
            gload16(Ag + (size_t)rb * 1024 + k0, At + rb * 64);
        }
#pragma unroll
        for (int j = 0; j < 4; ++j) {
            int rb = wave * 32 + j * 8;
            gload16(Bg + (size_t)rb * 1024 + k0, Bt + rb * 64);
        }
        __syncthreads();

#pragma unroll
        for (int ks = 0; ks < 4; ++ks) {
            const int cidx = (((ks * 2 + hl) ^ l7) * 8);
            bf16x8 af[MTw], bg[2];
#pragma unroll
            for (int mt = 0; mt < MTw; ++mt)
                af[mt] = *(const bf16x8*)(At + (wm + mt * 32 + l32) * 64 + cidx);
#pragma unroll
            for (int nt = 0; nt < 2; ++nt)
                bg[nt] = *(const bf16x8*)(Bt + (wn + nt * 32 + l32) * 64 + cidx);
#pragma unroll
            for (int mt = 0; mt < MTw; ++mt)
#pragma unroll
                for (int nt = 0; nt < 2; ++nt)
                    acc[mt][nt] = MFMA32(af[mt], bg[nt], acc[mt][nt]);
        }
    }

    if constexpr (OUTMODE == 0) {
        if (z == 2) {
#pragma unroll
            for (int mt = 0; mt < MTw; ++mt)
#pragma unroll
                for (int nt = 0; nt < 2; ++nt)
#pragma unroll
                    for (int g = 0; g < 4; ++g) {
                        int row = m0 + wm + mt * 32 + 4 * hl + 8 * g;
                        int col = n0 + wn + nt * 32 + l32;
                        bf16x4 pv;
#pragma unroll
                        for (int r = 0; r < 4; ++r) pv[r] = (bf16)acc[mt][nt][g * 4 + r];
                        *(bf16x4*)(C2 + ((size_t)((row >> 11) * 1024 + col)) * 2048 +
                                   (row & 2047)) = pv;
                    }
        } else {
            bf16* C = (z == 0) ? C0 : C1;
            const float cs = (z == 0) ? 0.04508422f : 1.0f;  // log2(e)/32
#pragma unroll
            for (int mt = 0; mt < MTw; ++mt)
#pragma unroll
                for (int nt = 0; nt < 2; ++nt) {
                    int col = n0 + wn + nt * 32 + l32;
#pragma unroll
                    for (int g = 0; g < 4; ++g) {
                        int row = m0 + wm + mt * 32 + 4 * hl + 8 * g;
#pragma unroll
                        for (int r = 0; r < 4; ++r)
                            C[(size_t)(row + r) * 1024 + col] =
                                (bf16)(acc[mt][nt][g * 4 + r] * cs);
                    }
                }
        }
    } else {
#pragma unroll
        for (int nt = 0; nt < 2; ++nt) {
            int col = n0 + wn + nt * 32 + l32;
            float bj = bias[col];
#pragma unroll
            for (int mt = 0; mt < MTw; ++mt)
#pragma unroll
                for (int g = 0; g < 4; ++g) {
                    int row = m0 + wm + mt * 32 + 4 * hl + 8 * g;
#pragma unroll
                    for (int r = 0; r < 4; ++r)
                        outf[(size_t)(row + r) * 1024 + col] =
                            acc[mt][nt][g * 4 + r] + bj;
                }
        }
    }
}

// ---------------------------------------------------------------------------
// Flash attention v8 = R5 structure + bare-HW exp2 + 128-key iteration.
// Block = 128 q of one (b,h); 4 waves x 32 q, each wave the full key tile.
// Each iteration stages TWO 64-key sub-tiles (identical R5-validated layout/
// swizzle, separate buffers) behind ONE barrier pair -> half the barrier
// drains (the ~20% structural stall of the 2-barrier K-loop). 32x32x16 MFMA.
// Max-free linear softmax (energies ~|0.7|), bit-packed mask, ones-MFMA
// row-sum. Q pre-scaled by log2(e)/32 -> __builtin_amdgcn_exp2f = ONE
// v_exp_f32 (plain exp2f lowers to OCML's guarded exp2: +4 VALU/score, the
// R7 regression).
// ---------------------------------------------------------------------------
__global__ __launch_bounds__(256) void flash_kernel(
    const bf16* __restrict__ Q, const bf16* __restrict__ K, const bf16* __restrict__ Vt,
    const unsigned long long* __restrict__ maskb, bf16* __restrict__ O)
{
    __shared__ bf16 Kl0[64 * 64];    // [key][d-chunk swizzled]
    __shared__ bf16 Kl1[64 * 64];
    __shared__ bf16 Vl0[64 * 64];    // [d][key-chunk swizzled]
    __shared__ bf16 Vl1[64 * 64];
    __shared__ bf16 Pl[128 * 72];    // [q][key+pad]

    const int tid  = threadIdx.x;
    const int lane = tid & 63;
    const int wave = tid >> 6;       // q-tile 0..3
    const int l32  = lane & 31;
    const int hl   = lane >> 5;
    const int l7   = lane & 7;
    const int b  = blockIdx.z;
    const int h  = blockIdx.y;
    const int q0 = blockIdx.x * 128;
    const int qt = q0 + wave * 32;

    // Q B-frags: B[k=d(hl*8+j)][n=q(l32)], 4 k-steps of 16
    const bf16* Qb = Q + (size_t)(b * 2048 + qt + l32) * 1024 + h * 64 + hl * 8;
    bf16x8 qf[4];
#pragma unroll
    for (int ks = 0; ks < 4; ++ks) qf[ks] = *(const bf16x8*)(Qb + ks * 16);

    bf16x8 ones;
#pragma unroll
    for (int j = 0; j < 8; ++j) ones[j] = (bf16)1.0f;

    f32x16 acc[2] = {};
    f32x16 lacc = {};

    // DMA staging (R5-validated mapping): wave stages rows wave*16..+15 of
    // each sub-tile, 2 calls per buffer (8 rows/call). Lane i -> row i>>3,
    // LDS chunk i&7, global chunk (i&7)^(i>>3).
    const int dmarow = lane >> 3;
    const int dmacol = (l7 ^ dmarow) * 8;
    const bf16* Kg = K + (size_t)(b * 2048 + wave * 16 + dmarow) * 1024 + h * 64 + dmacol;
    const bf16* Vg = Vt + (size_t)((b * 16 + h) * 64 + wave * 16 + dmarow) * 2048 + dmacol;
    bf16* Kw0 = Kl0 + (wave * 16) * 64;
    bf16* Kw1 = Kl1 + (wave * 16) * 64;
    bf16* Vw0 = Vl0 + (wave * 16) * 64;
    bf16* Vw1 = Vl1 + (wave * 16) * 64;
    const unsigned long long* Mg = maskb + (size_t)(qt + l32) * 32;

    bf16* Pq = Pl + (wave * 32 + l32) * 72;

    const bf16* Klh[2] = { Kl0, Kl1 };
    const bf16* Vlh[2] = { Vl0, Vl1 };

    for (int kt = 0; kt < 2048; kt += 128) {
        unsigned long long mwh[2] = { Mg[kt >> 6], Mg[(kt >> 6) + 1] };
        __syncthreads();                 // prev iteration's frag reads done
        gload16(Kg + (size_t)kt * 1024,        Kw0);
        gload16(Kg + (size_t)(kt + 8) * 1024,  Kw0 + 8 * 64);
        gload16(Kg + (size_t)(kt + 64) * 1024, Kw1);
        gload16(Kg + (size_t)(kt + 72) * 1024, Kw1 + 8 * 64);
        gload16(Vg + kt,                       Vw0);
        gload16(Vg + kt + 8 * 2048,            Vw0 + 8 * 64);
        gload16(Vg + kt + 64,                  Vw1);
        gload16(Vg + kt + 64 + 8 * 2048,       Vw1 + 8 * 64);
        __syncthreads();                 // vmcnt(0) drained before barrier

#pragma unroll
        for (int hf = 0; hf < 2; ++hf) {
            const bf16* Kc = Klh[hf];
            const bf16* Vc = Vlh[hf];
            const unsigned long long mw = mwh[hf];

            // S^T = K Q^T: two 32-key tiles, C[m=key][n=q]
#pragma unroll
            for (int t = 0; t < 2; ++t) {
                f32x16 s = {};
#pragma unroll
                for (int ks = 0; ks < 4; ++ks) {
                    bf16x8 ka = *(const bf16x8*)(Kc + (t * 32 + l32) * 64 +
                                                 (((ks * 2 + hl) ^ l7) * 8));
                    s = MFMA32(ka, qf[ks], s);
                }
                // mask + exp2 -> P[q][key] (reg g*4+r -> key t*32+4hl+8g+r)
                unsigned long long mwt = mw >> (t * 32 + 4 * hl);
#pragma unroll
                for (int g = 0; g < 4; ++g) {
                    bf16x4 pv;
#pragma unroll
                    for (int r = 0; r < 4; ++r) {
                        bool keep = (mwt >> (8 * g + r)) & 1ULL;
                        float e = __builtin_amdgcn_exp2f(s[g * 4 + r]);
                        pv[r] = keep ? (bf16)e : (bf16)0.0f;
                    }
                    *(bf16x4*)(Pq + t * 32 + 4 * hl + 8 * g) = pv;
                }
            }

            // PV: A=P[m=q][k=key] (wave-private roundtrip, no barrier),
            //     B=V^T[k=key][n=d] from swizzled Vc
            bf16x8 pa[4];
#pragma unroll
            for (int ks = 0; ks < 4; ++ks)
                pa[ks] = *(const bf16x8*)(Pq + ks * 16 + hl * 8);
#pragma unroll
            for (int dt = 0; dt < 2; ++dt)
#pragma unroll
                for (int ks = 0; ks < 4; ++ks) {
                    bf16x8 vb = *(const bf16x8*)(Vc + (dt * 32 + l32) * 64 +
                                                 (((ks * 2 + hl) ^ l7) * 8));
                    acc[dt] = MFMA32(pa[ks], vb, acc[dt]);
                }
#pragma unroll
            for (int ks = 0; ks < 4; ++ks)
                lacc = MFMA32(pa[ks], ones, lacc);   // row-sums, all n identical
        }
    }

    // Epilogue: row q_rel = 4hl + 8g + r, col d = dt*32 + l32
    const size_t obase = (size_t)(b * 2048 + qt) * 1024 + h * 64;
#pragma unroll
    for (int g = 0; g < 4; ++g)
#pragma unroll
        for (int r = 0; r < 4; ++r) {
            int qr = 4 * hl + 8 * g + r;
            float inv = 1.0f / lacc[g * 4 + r];
            O[obase + (size_t)qr * 1024 + l32]      = (bf16)(acc[0][g * 4 + r] * inv);
            O[obase + (size_t)qr * 1024 + 32 + l32] = (bf16)(acc[1][g * 4 + r] * inv);
        }
}

// ---------------------------------------------------------------------------
extern "C" void kernel_launch(void* const* d_in, const int* in_sizes, int n_in,
                              void* d_out, int out_size, void* d_ws, size_t ws_size,
                              hipStream_t stream)
{
    const float* q  = (const float*)d_in[0];
    const float* k  = (const float*)d_in[1];
    const float* v  = (const float*)d_in[2];
    const int* mask = (const int*)d_in[3];
    const float* wq = (const float*)d_in[4];
    const float* wk = (const float*)d_in[5];
    const float* wv = (const float*)d_in[6];
    const float* wo = (const float*)d_in[7];
    const float* bo = (const float*)d_in[8];
    float* out = (float*)d_out;

    char* p = (char*)d_ws;
    auto alloc = [&](size_t bytes) {
        char* r = p;
        p += (bytes + 255) & ~(size_t)255;
        return r;
    };
    const size_t SB = (size_t)4096 * 1024 * 2;
    const size_t WB = (size_t)1024 * 1024 * 2;
    bf16* qb  = (bf16*)alloc(SB);
    bf16* kb  = (bf16*)alloc(SB);
    bf16* vb  = (bf16*)alloc(SB);
    bf16* wqb = (bf16*)alloc(WB);
    bf16* wkb = (bf16*)alloc(WB);
    bf16* wvb = (bf16*)alloc(WB);
    bf16* wob = (bf16*)alloc(WB);
    bf16* Qp  = (bf16*)alloc(SB);
    bf16* Kp  = (bf16*)alloc(SB);
    bf16* Vtp = (bf16*)alloc(SB);
    bf16* Ob  = (bf16*)alloc(SB);
    unsigned long long* maskb = (unsigned long long*)alloc(2048 * 32 * 8);

    cvt_kernel<<<dim3(2048, 1, 7), 256, 0, stream>>>(
        q, k, v, wq, wk, wv, wo, qb, kb, vb, wqb, wkb, wvb, wob);

    maskpack_kernel<<<dim3(16384), 256, 0, stream>>>(mask, maskb);

    // z=2 (V) writes direct-transposed into Vtp
    gemm_kernel<0, 128><<<dim3(8, 32, 3), 256, 0, stream>>>(
        qb, kb, vb, wqb, wkb, wvb, Qp, Kp, Vtp, nullptr, nullptr);

    flash_kernel<<<dim3(16, 16, 2), 256, 0, stream>>>(Qp, Kp, Vtp, maskb, Ob);

    gemm_kernel<1, 64><<<dim3(8, 64, 1), 256, 0, stream>>>(
        Ob, nullptr, nullptr, wob, nullptr, nullptr,
        nullptr, nullptr, nullptr, bo, out);
}